// Round 6
// baseline (157.832 us; speedup 1.0000x reference)
//
#include <hip/hip_runtime.h>
#include <hip/hip_bf16.h>

#define NROWS 8192
#define DIM   128
#define NPAIR (NROWS / 2)
#define CSPLIT 32
#define COLS_PER_CS (NROWS / CSPLIT)    // 256
#define NTILES (COLS_PER_CS / 16)       // 16 col-tiles per cs chunk
#define MREP   4                        // 16-row blocks per wave -> 64 rows/wave
#define ROWS_PER_BLOCK 256              // 4 waves * 64 rows

typedef __attribute__((ext_vector_type(8))) short bf16x8;
typedef __attribute__((ext_vector_type(4))) float f32x4;

__device__ inline float exp2_fast(float x) {
#if __has_builtin(__builtin_amdgcn_exp2f)
    return __builtin_amdgcn_exp2f(x);
#else
    return exp2f(x);
#endif
}

__device__ inline unsigned short f2bf(float f) {
    unsigned int u = __float_as_uint(f);
    unsigned int r = (u + 0x7fffu + ((u >> 16) & 1u)) >> 16;
    return (unsigned short)r;
}

// exp(dot/128 + 1) = e * exp2(dot * SCL), SCL = log2(e)/128.
#define SCL_F 0.0112710550069450f      // 1.4426950408889634 / 128
#define E1_F  2.7182818284590452f

// Kernel 1: pack X (f32) directly into MFMA-fragment order.
// For 16-row tile t, k-group g (k = g*32 + lhi*8 + e), pack position:
//   P[((t*4 + g)*64 + lhi*16 + (r&15)) * 8 + e]
// so a wave's fragment load P[(t*4+g)*64 + lane] is 64 lanes x 16B fully
// contiguous (8 full 128B lines/instr) -- replaces R3/R5's 16-way 64B
// scatter that saturated the L2 transaction path.
// Pa = scaled by SCL (A operand), Pb = unscaled (B operand).
__global__ __launch_bounds__(256) void k_pack(const float* __restrict__ X,
                                              unsigned short* __restrict__ Pa,
                                              unsigned short* __restrict__ Pb) {
    int id = blockIdx.x * 256 + threadIdx.x;     // 0 .. 262143
    float4 v = reinterpret_cast<const float4*>(X)[id];
    int r  = id >> 5;                 // row 0..8191
    int k0 = (id & 31) * 4;           // 0,4,...,124
    int tile = r >> 4;
    int g    = k0 >> 5;               // 0..3
    int lhi  = (k0 >> 3) & 3;         // 0..3
    int e0   = k0 & 7;                // 0 or 4
    size_t base = ((size_t)(tile * 4 + g) * 64 + lhi * 16 + (r & 15)) * 8 + e0;
    ushort4 oa, ob;
    oa.x = f2bf(v.x * SCL_F); oa.y = f2bf(v.y * SCL_F);
    oa.z = f2bf(v.z * SCL_F); oa.w = f2bf(v.w * SCL_F);
    ob.x = f2bf(v.x); ob.y = f2bf(v.y); ob.z = f2bf(v.z); ob.w = f2bf(v.w);
    *reinterpret_cast<ushort4*>(Pa + base) = oa;
    *reinterpret_cast<ushort4*>(Pb + base) = ob;
}

// Kernel 2: partial[row][cs] = e * sum over 256-col chunk cs of exp2(SCL*dot).
// All hot-loop global loads are fully coalesced 1KB/instr from the packed
// arrays. Geometry = R3 (best known): MREP=4, rolled ct loop, no occupancy
// attributes (R2/R4 spilled; R5's cap didn't move the allocator).
__global__ void k_rowsum(const unsigned short* __restrict__ Pa,
                         const unsigned short* __restrict__ Pb,
                         float* __restrict__ partial) {
    const int wave = threadIdx.x >> 6;
    const int lane = threadIdx.x & 63;
    const int l15  = lane & 15;
    const int lhi  = lane >> 4;   // 0..3
    const int rowbase = blockIdx.x * ROWS_PER_BLOCK + wave * (MREP * 16);
    const int rb0 = rowbase >> 4;            // first 16-row tile of this wave
    const int cs = blockIdx.y;
    const int ct0 = cs * NTILES;             // first col-tile of this chunk

    const bf16x8* PA = reinterpret_cast<const bf16x8*>(Pa);
    const bf16x8* PB = reinterpret_cast<const bf16x8*>(Pb);

    // A fragments: 4 row-tiles x 4 k-groups, each a coalesced 1KB wave-load.
    bf16x8 a[MREP][4];
#pragma unroll
    for (int m = 0; m < MREP; ++m)
#pragma unroll
        for (int g = 0; g < 4; ++g)
            a[m][g] = PA[(size_t)((rb0 + m) * 4 + g) * 64 + lane];

    f32x4 esum[MREP];
#pragma unroll
    for (int m = 0; m < MREP; ++m) esum[m] = (f32x4){0.f, 0.f, 0.f, 0.f};

    for (int ct = 0; ct < NTILES; ++ct) {
        const size_t tb = (size_t)(ct0 + ct) * 4 * 64 + lane;
        bf16x8 b0 = PB[tb];
        bf16x8 b1 = PB[tb + 64];
        bf16x8 b2 = PB[tb + 128];
        bf16x8 b3 = PB[tb + 192];
#pragma unroll
        for (int m = 0; m < MREP; ++m) {
            f32x4 d = {0.f, 0.f, 0.f, 0.f};
            d = __builtin_amdgcn_mfma_f32_16x16x32_bf16(a[m][0], b0, d, 0, 0, 0);
            d = __builtin_amdgcn_mfma_f32_16x16x32_bf16(a[m][1], b1, d, 0, 0, 0);
            d = __builtin_amdgcn_mfma_f32_16x16x32_bf16(a[m][2], b2, d, 0, 0, 0);
            d = __builtin_amdgcn_mfma_f32_16x16x32_bf16(a[m][3], b3, d, 0, 0, 0);
            esum[m][0] += exp2_fast(d[0]);
            esum[m][1] += exp2_fast(d[1]);
            esum[m][2] += exp2_fast(d[2]);
            esum[m][3] += exp2_fast(d[3]);
        }
    }

    // Reduce the 16 column-lanes (same lhi, varying l15); one slot per row.
#pragma unroll
    for (int m = 0; m < MREP; ++m) {
#pragma unroll
        for (int j = 0; j < 4; ++j) {
            float v = esum[m][j];
            v += __shfl_xor(v, 1, 64);
            v += __shfl_xor(v, 2, 64);
            v += __shfl_xor(v, 4, 64);
            v += __shfl_xor(v, 8, 64);
            if (l15 == 0) {
                int row = rowbase + m * 16 + lhi * 4 + j;
                partial[(size_t)row * CSPLIT + cs] = v * E1_F;
            }
        }
    }
}

// Kernel 3: per-pair exact f32 2x2 block + D_pos + J^2, block-reduced.
__global__ __launch_bounds__(256) void k_loss1(const float* __restrict__ X,
                                               const float* __restrict__ partial,
                                               float* __restrict__ lpart) {
    int p = blockIdx.x * 256 + threadIdx.x;   // 0..4095
    const float4* a = reinterpret_cast<const float4*>(X + (size_t)(2 * p) * DIM);
    const float4* b = reinterpret_cast<const float4*>(X + (size_t)(2 * p + 1) * DIM);
    float d00 = 0.f, d01 = 0.f, d11 = 0.f;
#pragma unroll 8
    for (int i = 0; i < DIM / 4; ++i) {
        float4 av = a[i], bv = b[i];
        d00 += av.x * av.x + av.y * av.y + av.z * av.z + av.w * av.w;
        d01 += av.x * bv.x + av.y * bv.y + av.z * bv.z + av.w * bv.w;
        d11 += bv.x * bv.x + bv.y * bv.y + bv.z * bv.z + bv.w * bv.w;
    }
    float D01 = d01 * (1.0f / DIM);
    float blocksum = __expf(d00 * (1.0f / DIM) + 1.0f)
                   + 2.0f * __expf(D01 + 1.0f)
                   + __expf(d11 * (1.0f / DIM) + 1.0f);

    // Row sums for rows 2p, 2p+1: 64 contiguous floats.
    const float4* pp = reinterpret_cast<const float4*>(partial + (size_t)(2 * p) * CSPLIT);
    float S = 0.0f;
#pragma unroll
    for (int i = 0; i < 2 * CSPLIT / 4; ++i) {
        float4 v = pp[i];
        S += v.x + v.y + v.z + v.w;
    }
    S -= blocksum;
    float J = logf(1e-8f + S) - D01;
    float t = fmaxf(J, 0.0f);
    float acc = t * t;

    __shared__ float red[4];
    float v = acc;
#pragma unroll
    for (int off = 32; off >= 1; off >>= 1) v += __shfl_down(v, off, 64);
    if ((threadIdx.x & 63) == 0) red[threadIdx.x >> 6] = v;
    __syncthreads();
    if (threadIdx.x == 0)
        lpart[blockIdx.x] = red[0] + red[1] + red[2] + red[3];
}

// Kernel 4: final 16-element sum -> loss.
__global__ __launch_bounds__(64) void k_final(const float* __restrict__ lpart,
                                              float* __restrict__ out) {
    float v = (threadIdx.x < 16) ? lpart[threadIdx.x] : 0.0f;
#pragma unroll
    for (int off = 8; off >= 1; off >>= 1) v += __shfl_down(v, off, 64);
    if (threadIdx.x == 0) out[0] = v * (1.0f / (2.0f * NPAIR));
}

extern "C" void kernel_launch(void* const* d_in, const int* in_sizes, int n_in,
                              void* d_out, int out_size, void* d_ws, size_t ws_size,
                              hipStream_t stream) {
    const float* X = (const float*)d_in[0];
    float* out = (float*)d_out;

    unsigned short* Pa = (unsigned short*)d_ws;                        // 2 MB
    unsigned short* Pb = Pa + (size_t)NROWS * DIM;                     // 2 MB
    float* partial = (float*)(Pb + (size_t)NROWS * DIM);               // 1 MB
    float* lpart = partial + (size_t)NROWS * CSPLIT;                   // 64 B

    k_pack<<<dim3((NROWS * DIM / 4) / 256), dim3(256), 0, stream>>>(X, Pa, Pb);
    k_rowsum<<<dim3(NROWS / ROWS_PER_BLOCK, CSPLIT), dim3(256), 0, stream>>>(Pa, Pb, partial);
    k_loss1<<<dim3(NPAIR / 256), dim3(256), 0, stream>>>(X, partial, lpart);
    k_final<<<dim3(1), dim3(64), 0, stream>>>(lpart, out);
}

// Round 7
// 82.230 us; speedup vs baseline: 1.9194x; 1.9194x over previous
//
#include <hip/hip_runtime.h>
#include <hip/hip_bf16.h>

#define NROWS 8192
#define DIM   128
#define NPAIR (NROWS / 2)
#define RSPLIT 16                         // row chunks (output partials per col)
#define ROWS_PER_CHUNK (NROWS / RSPLIT)   // 512
#define ITERS (ROWS_PER_CHUNK / 16)       // 32 row-tiles streamed per wave
#define CWAVE 32                          // resident cols per wave (2 tiles, 32 VGPRs)
#define CBLOCK 128                        // 4 waves * 32 cols

typedef __attribute__((ext_vector_type(8))) short bf16x8;
typedef __attribute__((ext_vector_type(4))) float f32x4;

__device__ inline float exp2_fast(float x) {
#if __has_builtin(__builtin_amdgcn_exp2f)
    return __builtin_amdgcn_exp2f(x);
#else
    return exp2f(x);
#endif
}

__device__ inline unsigned short f2bf(float f) {
    unsigned int u = __float_as_uint(f);
    unsigned int r = (u + 0x7fffu + ((u >> 16) & 1u)) >> 16;
    return (unsigned short)r;
}

// exp(d/128 + 1) = exp2(d*SCL + L2E)
#define SCL_F 0.0112710550069450f      // log2(e)/128
#define L2E_F 1.4426950408889634f      // log2(e)

// Kernel 1: X (f32) -> Xc (bf16). Single array: E_bf16 is then EXACTLY
// symmetric (MFMA k-reduction order is operand-symmetric), so column sums
// == row sums bitwise-deterministically.
__global__ __launch_bounds__(256) void k_convert(const float* __restrict__ X,
                                                 unsigned short* __restrict__ Xc) {
    int id = blockIdx.x * 256 + threadIdx.x;       // 0 .. 262143
    float4 v = reinterpret_cast<const float4*>(X)[id];
    ushort4 o;
    o.x = f2bf(v.x); o.y = f2bf(v.y); o.z = f2bf(v.z); o.w = f2bf(v.w);
    reinterpret_cast<ushort4*>(Xc)[id] = o;
}

// Kernel 2: column-sum form. Wave owns 32 resident cols (32 VGPRs, pinned
// so the allocator can neither remat nor fold them), streams row-tiles,
// accumulates per-lane column sums in 2 scalar regs. partial[col][ry] =
// sum over rows in chunk ry of exp(D/128+1). By symmetry of E this is the
// row sum decomposition the epilogue needs.
// Register demand ~75: fits the 128-VGPR cap of (256,4) with no spill and
// no remat -> issued vector-memory traffic drops to 8KB/wave-iter (512MB
// total vs R3's 1.3GB on the ~39TB/s request-port ceiling).
__global__ __launch_bounds__(256, 4)
void k_colsum(const unsigned short* __restrict__ Xc,
              float* __restrict__ partial) {
    const int wave = threadIdx.x >> 6;
    const int lane = threadIdx.x & 63;
    const int l15  = lane & 15;
    const int lhi  = lane >> 4;   // 0..3
    const int cbase = blockIdx.x * CBLOCK + wave * CWAVE;  // first resident col
    const int ry   = blockIdx.y;
    const int row0 = ry * ROWS_PER_CHUNK;

    // Resident B fragments: 2 col-tiles x 4 k-groups = 32 VGPRs.
    bf16x8 b00, b01, b02, b03, b10, b11, b12, b13;
    {
        const unsigned short* c0 = Xc + (size_t)(cbase + l15) * DIM + lhi * 8;
        const unsigned short* c1 = c0 + 16 * DIM;
        b00 = *reinterpret_cast<const bf16x8*>(c0);
        b01 = *reinterpret_cast<const bf16x8*>(c0 + 32);
        b02 = *reinterpret_cast<const bf16x8*>(c0 + 64);
        b03 = *reinterpret_cast<const bf16x8*>(c0 + 96);
        b10 = *reinterpret_cast<const bf16x8*>(c1);
        b11 = *reinterpret_cast<const bf16x8*>(c1 + 32);
        b12 = *reinterpret_cast<const bf16x8*>(c1 + 64);
        b13 = *reinterpret_cast<const bf16x8*>(c1 + 96);
    }
    // Pin: values now originate from opaque asm -> cannot be rematerialized.
    asm volatile("" : "+v"(b00)); asm volatile("" : "+v"(b01));
    asm volatile("" : "+v"(b02)); asm volatile("" : "+v"(b03));
    asm volatile("" : "+v"(b10)); asm volatile("" : "+v"(b11));
    asm volatile("" : "+v"(b12)); asm volatile("" : "+v"(b13));

    float esum0 = 0.0f, esum1 = 0.0f;

    const unsigned short* arow = Xc + (size_t)(row0 + l15) * DIM + lhi * 8;

    for (int it = 0; it < ITERS; ++it) {
        const unsigned short* ap = arow + (size_t)it * 16 * DIM;
        bf16x8 a0 = *reinterpret_cast<const bf16x8*>(ap);
        bf16x8 a1 = *reinterpret_cast<const bf16x8*>(ap + 32);
        bf16x8 a2 = *reinterpret_cast<const bf16x8*>(ap + 64);
        bf16x8 a3 = *reinterpret_cast<const bf16x8*>(ap + 96);

        f32x4 d0 = {0.f, 0.f, 0.f, 0.f};
        f32x4 d1 = {0.f, 0.f, 0.f, 0.f};
        d0 = __builtin_amdgcn_mfma_f32_16x16x32_bf16(a0, b00, d0, 0, 0, 0);
        d1 = __builtin_amdgcn_mfma_f32_16x16x32_bf16(a0, b10, d1, 0, 0, 0);
        d0 = __builtin_amdgcn_mfma_f32_16x16x32_bf16(a1, b01, d0, 0, 0, 0);
        d1 = __builtin_amdgcn_mfma_f32_16x16x32_bf16(a1, b11, d1, 0, 0, 0);
        d0 = __builtin_amdgcn_mfma_f32_16x16x32_bf16(a2, b02, d0, 0, 0, 0);
        d1 = __builtin_amdgcn_mfma_f32_16x16x32_bf16(a2, b12, d1, 0, 0, 0);
        d0 = __builtin_amdgcn_mfma_f32_16x16x32_bf16(a3, b03, d0, 0, 0, 0);
        d1 = __builtin_amdgcn_mfma_f32_16x16x32_bf16(a3, b13, d1, 0, 0, 0);

        // d0[j] = D[row0+it*16+(lhi*4+j)][cbase+l15]; d1 -> col +16.
        esum0 += exp2_fast(fmaf(d0[0], SCL_F, L2E_F));
        esum0 += exp2_fast(fmaf(d0[1], SCL_F, L2E_F));
        esum0 += exp2_fast(fmaf(d0[2], SCL_F, L2E_F));
        esum0 += exp2_fast(fmaf(d0[3], SCL_F, L2E_F));
        esum1 += exp2_fast(fmaf(d1[0], SCL_F, L2E_F));
        esum1 += exp2_fast(fmaf(d1[1], SCL_F, L2E_F));
        esum1 += exp2_fast(fmaf(d1[2], SCL_F, L2E_F));
        esum1 += exp2_fast(fmaf(d1[3], SCL_F, L2E_F));
    }

    // Sum the 4 lhi-lane groups (same l15 = same column).
    esum0 += __shfl_xor(esum0, 16, 64);
    esum0 += __shfl_xor(esum0, 32, 64);
    esum1 += __shfl_xor(esum1, 16, 64);
    esum1 += __shfl_xor(esum1, 32, 64);

    if (lane < 16) {
        partial[(size_t)(cbase + lane) * RSPLIT + ry] = esum0;
        partial[(size_t)(cbase + 16 + lane) * RSPLIT + ry] = esum1;
    }
}

// Kernel 3: per-pair exact f32 2x2 block + D_pos + J^2, block-reduced.
__global__ __launch_bounds__(256) void k_loss1(const float* __restrict__ X,
                                               const float* __restrict__ partial,
                                               float* __restrict__ lpart) {
    int p = blockIdx.x * 256 + threadIdx.x;   // 0..4095
    const float4* a = reinterpret_cast<const float4*>(X + (size_t)(2 * p) * DIM);
    const float4* b = reinterpret_cast<const float4*>(X + (size_t)(2 * p + 1) * DIM);
    float d00 = 0.f, d01 = 0.f, d11 = 0.f;
#pragma unroll 8
    for (int i = 0; i < DIM / 4; ++i) {
        float4 av = a[i], bv = b[i];
        d00 += av.x * av.x + av.y * av.y + av.z * av.z + av.w * av.w;
        d01 += av.x * bv.x + av.y * bv.y + av.z * bv.z + av.w * bv.w;
        d11 += bv.x * bv.x + bv.y * bv.y + bv.z * bv.z + bv.w * bv.w;
    }
    float D01 = d01 * (1.0f / DIM);
    float blocksum = __expf(d00 * (1.0f / DIM) + 1.0f)
                   + 2.0f * __expf(D01 + 1.0f)
                   + __expf(d11 * (1.0f / DIM) + 1.0f);

    // Row sums for rows 2p, 2p+1: 2*RSPLIT = 32 contiguous floats.
    const float4* pp = reinterpret_cast<const float4*>(partial + (size_t)(2 * p) * RSPLIT);
    float S = 0.0f;
#pragma unroll
    for (int i = 0; i < 2 * RSPLIT / 4; ++i) {
        float4 v = pp[i];
        S += v.x + v.y + v.z + v.w;
    }
    S -= blocksum;
    float J = logf(1e-8f + S) - D01;
    float t = fmaxf(J, 0.0f);
    float acc = t * t;

    __shared__ float red[4];
    float v = acc;
#pragma unroll
    for (int off = 32; off >= 1; off >>= 1) v += __shfl_down(v, off, 64);
    if ((threadIdx.x & 63) == 0) red[threadIdx.x >> 6] = v;
    __syncthreads();
    if (threadIdx.x == 0)
        lpart[blockIdx.x] = red[0] + red[1] + red[2] + red[3];
}

// Kernel 4: final 16-element sum -> loss.
__global__ __launch_bounds__(64) void k_final(const float* __restrict__ lpart,
                                              float* __restrict__ out) {
    float v = (threadIdx.x < 16) ? lpart[threadIdx.x] : 0.0f;
#pragma unroll
    for (int off = 8; off >= 1; off >>= 1) v += __shfl_down(v, off, 64);
    if (threadIdx.x == 0) out[0] = v * (1.0f / (2.0f * NPAIR));
}

extern "C" void kernel_launch(void* const* d_in, const int* in_sizes, int n_in,
                              void* d_out, int out_size, void* d_ws, size_t ws_size,
                              hipStream_t stream) {
    const float* X = (const float*)d_in[0];
    float* out = (float*)d_out;

    unsigned short* Xc = (unsigned short*)d_ws;                        // 2 MB
    float* partial = (float*)(Xc + (size_t)NROWS * DIM);               // 512 KB
    float* lpart = partial + (size_t)NROWS * RSPLIT;                   // 64 B

    k_convert<<<dim3((NROWS * DIM / 4) / 256), dim3(256), 0, stream>>>(X, Xc);
    k_colsum<<<dim3(NROWS / CBLOCK, RSPLIT), dim3(256), 0, stream>>>(Xc, partial);
    k_loss1<<<dim3(NPAIR / 256), dim3(256), 0, stream>>>(X, partial, lpart);
    k_final<<<dim3(1), dim3(64), 0, stream>>>(lpart, out);
}

// Round 8
// 47.943 us; speedup vs baseline: 3.2921x; 1.7152x over previous
//
#include <hip/hip_runtime.h>
#include <hip/hip_bf16.h>

#define NROWS 8192
#define DIM   128
#define NPAIR (NROWS / 2)
#define CSPLIT 16                        // col chunks -> partial[row][16]
#define COLS_PER_CS (NROWS / CSPLIT)     // 512 cols per block
#define CTILE 128                        // cols per LDS tile (32 KB)
#define TILES_PER_CS (COLS_PER_CS / CTILE) // 4
#define MREP 2                           // 16-row tiles per wave -> 32 rows
#define ROWS_PER_BLOCK 128               // 4 waves * 32 rows

typedef __attribute__((ext_vector_type(8))) short bf16x8;
typedef __attribute__((ext_vector_type(4))) float f32x4;

__device__ inline float exp2_fast(float x) {
#if __has_builtin(__builtin_amdgcn_exp2f)
    return __builtin_amdgcn_exp2f(x);
#else
    return exp2f(x);
#endif
}

__device__ inline unsigned short f2bf(float f) {
    unsigned int u = __float_as_uint(f);
    unsigned int r = (u + 0x7fffu + ((u >> 16) & 1u)) >> 16;
    return (unsigned short)r;
}

// exp(d/128 + 1) = exp2(d*SCL + L2E)
#define SCL_F 0.0112710550069450f      // log2(e)/128
#define L2E_F 1.4426950408889634f      // log2(e)

// Kernel 1: X (f32) -> Xc (bf16).
__global__ __launch_bounds__(256) void k_convert(const float* __restrict__ X,
                                                 unsigned short* __restrict__ Xc) {
    int id = blockIdx.x * 256 + threadIdx.x;       // 0 .. 262143
    float4 v = reinterpret_cast<const float4*>(X)[id];
    ushort4 o;
    o.x = f2bf(v.x); o.y = f2bf(v.y); o.z = f2bf(v.z); o.w = f2bf(v.w);
    reinterpret_cast<ushort4*>(Xc)[id] = o;
}

// Kernel 2: partial[row][cs] = sum over 512-col chunk cs of exp(D/128+1).
// Structure (canonical GEMM staging, adapted):
//  - A fragments (32 rows/wave) resident in 32 VGPRs, pinned (R7-proven).
//  - B tiles (128 cols x 128 k = 32 KB) staged in LDS per block:
//    coalesced global read + XOR-swizzled ds_write_b128 (2-way, free);
//    fragment ds_read_b128 uses the same XOR (involution) -> 2-way, free.
//  - This removes the per-wave-iteration scattered global stream that
//    cost ~400 CU-cycles/iter across R1-R7.
__global__ __launch_bounds__(256) void k_rowsum(const unsigned short* __restrict__ Xc,
                                                float* __restrict__ partial) {
    __shared__ unsigned short Bt[CTILE * DIM];   // 32 KB
    const int tid  = threadIdx.x;
    const int wave = tid >> 6;
    const int lane = tid & 63;
    const int l15  = lane & 15;
    const int lhi  = lane >> 4;   // 0..3
    const int rowbase = blockIdx.x * ROWS_PER_BLOCK + wave * (MREP * 16);
    const int cs = blockIdx.y;

    // A fragments: 2 row-tiles x 4 k-groups = 32 VGPRs, loaded once, pinned.
    bf16x8 a00, a01, a02, a03, a10, a11, a12, a13;
    {
        const unsigned short* r0 = Xc + (size_t)(rowbase + l15) * DIM + lhi * 8;
        const unsigned short* r1 = r0 + 16 * DIM;
        a00 = *reinterpret_cast<const bf16x8*>(r0);
        a01 = *reinterpret_cast<const bf16x8*>(r0 + 32);
        a02 = *reinterpret_cast<const bf16x8*>(r0 + 64);
        a03 = *reinterpret_cast<const bf16x8*>(r0 + 96);
        a10 = *reinterpret_cast<const bf16x8*>(r1);
        a11 = *reinterpret_cast<const bf16x8*>(r1 + 32);
        a12 = *reinterpret_cast<const bf16x8*>(r1 + 64);
        a13 = *reinterpret_cast<const bf16x8*>(r1 + 96);
    }
    asm volatile("" : "+v"(a00), "+v"(a01), "+v"(a02), "+v"(a03));
    asm volatile("" : "+v"(a10), "+v"(a11), "+v"(a12), "+v"(a13));

    f32x4 esum0 = {0.f, 0.f, 0.f, 0.f};
    f32x4 esum1 = {0.f, 0.f, 0.f, 0.f};

    for (int it = 0; it < TILES_PER_CS; ++it) {
        const int c0 = cs * COLS_PER_CS + it * CTILE;

        // Stage 32 KB: 2048 x 16B chunks; thread handles 8 chunks.
        // Global read fully coalesced (consecutive chunks); LDS write at
        // chunk (col*16 + (seg ^ (col&7))): 2-way bank aliasing = free.
#pragma unroll 2
        for (int j = 0; j < 8; ++j) {
            int d   = j * 256 + tid;          // chunk id 0..2047
            int col = d >> 4;
            int seg = d & 15;
            bf16x8 v = *reinterpret_cast<const bf16x8*>(
                Xc + (size_t)(c0 + col) * DIM + seg * 8);
            *reinterpret_cast<bf16x8*>(
                &Bt[(((size_t)col << 4) | (seg ^ (col & 7))) * 8]) = v;
        }
        __syncthreads();

        for (int ct = 0; ct < CTILE / 16; ++ct) {
            const int c = ct * 16 + l15;      // col within tile
            const int x = c & 7;
            const unsigned short* lb = &Bt[(size_t)c * DIM];
            // g-th fragment: global seg s = g*4 + lhi, stored at slot s^x.
            bf16x8 b0 = *reinterpret_cast<const bf16x8*>(lb + (((lhi     ) ^ x) * 8));
            bf16x8 b1 = *reinterpret_cast<const bf16x8*>(lb + (((lhi + 4 ) ^ x) * 8));
            bf16x8 b2 = *reinterpret_cast<const bf16x8*>(lb + (((lhi + 8 ) ^ x) * 8));
            bf16x8 b3 = *reinterpret_cast<const bf16x8*>(lb + (((lhi + 12) ^ x) * 8));

            f32x4 d0 = {0.f, 0.f, 0.f, 0.f};
            f32x4 d1 = {0.f, 0.f, 0.f, 0.f};
            d0 = __builtin_amdgcn_mfma_f32_16x16x32_bf16(a00, b0, d0, 0, 0, 0);
            d1 = __builtin_amdgcn_mfma_f32_16x16x32_bf16(a10, b0, d1, 0, 0, 0);
            d0 = __builtin_amdgcn_mfma_f32_16x16x32_bf16(a01, b1, d0, 0, 0, 0);
            d1 = __builtin_amdgcn_mfma_f32_16x16x32_bf16(a11, b1, d1, 0, 0, 0);
            d0 = __builtin_amdgcn_mfma_f32_16x16x32_bf16(a02, b2, d0, 0, 0, 0);
            d1 = __builtin_amdgcn_mfma_f32_16x16x32_bf16(a12, b2, d1, 0, 0, 0);
            d0 = __builtin_amdgcn_mfma_f32_16x16x32_bf16(a03, b3, d0, 0, 0, 0);
            d1 = __builtin_amdgcn_mfma_f32_16x16x32_bf16(a13, b3, d1, 0, 0, 0);

            esum0[0] += exp2_fast(fmaf(d0[0], SCL_F, L2E_F));
            esum0[1] += exp2_fast(fmaf(d0[1], SCL_F, L2E_F));
            esum0[2] += exp2_fast(fmaf(d0[2], SCL_F, L2E_F));
            esum0[3] += exp2_fast(fmaf(d0[3], SCL_F, L2E_F));
            esum1[0] += exp2_fast(fmaf(d1[0], SCL_F, L2E_F));
            esum1[1] += exp2_fast(fmaf(d1[1], SCL_F, L2E_F));
            esum1[2] += exp2_fast(fmaf(d1[2], SCL_F, L2E_F));
            esum1[3] += exp2_fast(fmaf(d1[3], SCL_F, L2E_F));
        }
        __syncthreads();
    }

    // Reduce the 16 column-lanes (varying l15); one slot per row.
#pragma unroll
    for (int m = 0; m < MREP; ++m) {
#pragma unroll
        for (int j = 0; j < 4; ++j) {
            float v = (m == 0) ? esum0[j] : esum1[j];
            v += __shfl_xor(v, 1, 64);
            v += __shfl_xor(v, 2, 64);
            v += __shfl_xor(v, 4, 64);
            v += __shfl_xor(v, 8, 64);
            if (l15 == 0) {
                int row = rowbase + m * 16 + lhi * 4 + j;
                partial[(size_t)row * CSPLIT + cs] = v;
            }
        }
    }
}

// Kernel 3: per-pair exact f32 2x2 block + D_pos + J^2, block-reduced.
__global__ __launch_bounds__(256) void k_loss1(const float* __restrict__ X,
                                               const float* __restrict__ partial,
                                               float* __restrict__ lpart) {
    int p = blockIdx.x * 256 + threadIdx.x;   // 0..4095
    const float4* a = reinterpret_cast<const float4*>(X + (size_t)(2 * p) * DIM);
    const float4* b = reinterpret_cast<const float4*>(X + (size_t)(2 * p + 1) * DIM);
    float d00 = 0.f, d01 = 0.f, d11 = 0.f;
#pragma unroll 8
    for (int i = 0; i < DIM / 4; ++i) {
        float4 av = a[i], bv = b[i];
        d00 += av.x * av.x + av.y * av.y + av.z * av.z + av.w * av.w;
        d01 += av.x * bv.x + av.y * bv.y + av.z * bv.z + av.w * bv.w;
        d11 += bv.x * bv.x + bv.y * bv.y + bv.z * bv.z + bv.w * bv.w;
    }
    float D01 = d01 * (1.0f / DIM);
    float blocksum = __expf(d00 * (1.0f / DIM) + 1.0f)
                   + 2.0f * __expf(D01 + 1.0f)
                   + __expf(d11 * (1.0f / DIM) + 1.0f);

    // Row sums for rows 2p, 2p+1: 2*CSPLIT = 32 contiguous floats.
    const float4* pp = reinterpret_cast<const float4*>(partial + (size_t)(2 * p) * CSPLIT);
    float S = 0.0f;
#pragma unroll
    for (int i = 0; i < 2 * CSPLIT / 4; ++i) {
        float4 v = pp[i];
        S += v.x + v.y + v.z + v.w;
    }
    S -= blocksum;
    float J = logf(1e-8f + S) - D01;
    float t = fmaxf(J, 0.0f);
    float acc = t * t;

    __shared__ float red[4];
    float v = acc;
#pragma unroll
    for (int off = 32; off >= 1; off >>= 1) v += __shfl_down(v, off, 64);
    if ((threadIdx.x & 63) == 0) red[threadIdx.x >> 6] = v;
    __syncthreads();
    if (threadIdx.x == 0)
        lpart[blockIdx.x] = red[0] + red[1] + red[2] + red[3];
}

// Kernel 4: final 16-element sum -> loss.
__global__ __launch_bounds__(64) void k_final(const float* __restrict__ lpart,
                                              float* __restrict__ out) {
    float v = (threadIdx.x < 16) ? lpart[threadIdx.x] : 0.0f;
#pragma unroll
    for (int off = 8; off >= 1; off >>= 1) v += __shfl_down(v, off, 64);
    if (threadIdx.x == 0) out[0] = v * (1.0f / (2.0f * NPAIR));
}

extern "C" void kernel_launch(void* const* d_in, const int* in_sizes, int n_in,
                              void* d_out, int out_size, void* d_ws, size_t ws_size,
                              hipStream_t stream) {
    const float* X = (const float*)d_in[0];
    float* out = (float*)d_out;

    unsigned short* Xc = (unsigned short*)d_ws;                        // 2 MB
    float* partial = (float*)(Xc + (size_t)NROWS * DIM);               // 512 KB
    float* lpart = partial + (size_t)NROWS * CSPLIT;                   // 64 B

    k_convert<<<dim3((NROWS * DIM / 4) / 256), dim3(256), 0, stream>>>(X, Xc);
    k_rowsum<<<dim3(NROWS / ROWS_PER_BLOCK, CSPLIT), dim3(256), 0, stream>>>(Xc, partial);
    k_loss1<<<dim3(NPAIR / 256), dim3(256), 0, stream>>>(X, partial, lpart);
    k_final<<<dim3(1), dim3(64), 0, stream>>>(lpart, out);
}

// Round 9
// 41.603 us; speedup vs baseline: 3.7937x; 1.1524x over previous
//
#include <hip/hip_runtime.h>
#include <hip/hip_bf16.h>

#define NROWS 8192
#define DIM   128
#define NPAIR (NROWS / 2)
#define CSPLIT 16                        // col chunks -> partial[row][16]
#define COLS_PER_CS (NROWS / CSPLIT)     // 512 cols per block
#define CTILE 64                         // cols per LDS tile (16 KB)
#define NT (COLS_PER_CS / CTILE)         // 8 tiles per chunk
#define MREP 2                           // 16-row tiles per wave -> 32 rows
#define ROWS_PER_BLOCK 128               // 4 waves * 32 rows

typedef __attribute__((ext_vector_type(8))) short bf16x8;
typedef __attribute__((ext_vector_type(4))) float f32x4;

__device__ inline float exp2_fast(float x) {
#if __has_builtin(__builtin_amdgcn_exp2f)
    return __builtin_amdgcn_exp2f(x);
#else
    return exp2f(x);
#endif
}

__device__ inline unsigned short f2bf(float f) {
    unsigned int u = __float_as_uint(f);
    unsigned int r = (u + 0x7fffu + ((u >> 16) & 1u)) >> 16;
    return (unsigned short)r;
}

// exp(d/128 + 1) = e * exp2(d * SCL); SCL baked into A operand (Xa),
// the e factor folded into the partial write.
#define SCL_F 0.0112710550069450f      // log2(e)/128
#define E1_F  2.7182818284590452f

// Kernel 1: X (f32) -> Xa (bf16, scaled) and Xc (bf16, unscaled).
__global__ __launch_bounds__(256) void k_convert(const float* __restrict__ X,
                                                 unsigned short* __restrict__ Xa,
                                                 unsigned short* __restrict__ Xc) {
    int id = blockIdx.x * 256 + threadIdx.x;       // 0 .. 262143
    float4 v = reinterpret_cast<const float4*>(X)[id];
    ushort4 oa, oc;
    oa.x = f2bf(v.x * SCL_F); oa.y = f2bf(v.y * SCL_F);
    oa.z = f2bf(v.z * SCL_F); oa.w = f2bf(v.w * SCL_F);
    oc.x = f2bf(v.x); oc.y = f2bf(v.y); oc.z = f2bf(v.z); oc.w = f2bf(v.w);
    reinterpret_cast<ushort4*>(Xa)[id] = oa;
    reinterpret_cast<ushort4*>(Xc)[id] = oc;
}

// Kernel 2: partial[row][cs] = e * sum over 512-col chunk of exp2(SCL*dot).
// R8 + pipelined staging (T14 issue-early/write-late): stage regs for tile
// t+1 are loaded while tile t computes from LDS; vmcnt wait lands at the
// next ds_write, not before compute. A fragments pinned in 32 VGPRs.
__global__ __launch_bounds__(256, 4) void k_rowsum(const unsigned short* __restrict__ Xa,
                                                   const unsigned short* __restrict__ Xc,
                                                   float* __restrict__ partial) {
    __shared__ unsigned short Bt[CTILE * DIM];   // 16 KB
    const int tid  = threadIdx.x;
    const int wave = tid >> 6;
    const int lane = tid & 63;
    const int l15  = lane & 15;
    const int lhi  = lane >> 4;   // 0..3
    const int rowbase = blockIdx.x * ROWS_PER_BLOCK + wave * (MREP * 16);
    const int cs = blockIdx.y;

    // A fragments: 2 row-tiles x 4 k-groups = 32 VGPRs, loaded once, pinned.
    bf16x8 a00, a01, a02, a03, a10, a11, a12, a13;
    {
        const unsigned short* r0 = Xa + (size_t)(rowbase + l15) * DIM + lhi * 8;
        const unsigned short* r1 = r0 + 16 * DIM;
        a00 = *reinterpret_cast<const bf16x8*>(r0);
        a01 = *reinterpret_cast<const bf16x8*>(r0 + 32);
        a02 = *reinterpret_cast<const bf16x8*>(r0 + 64);
        a03 = *reinterpret_cast<const bf16x8*>(r0 + 96);
        a10 = *reinterpret_cast<const bf16x8*>(r1);
        a11 = *reinterpret_cast<const bf16x8*>(r1 + 32);
        a12 = *reinterpret_cast<const bf16x8*>(r1 + 64);
        a13 = *reinterpret_cast<const bf16x8*>(r1 + 96);
    }
    asm volatile("" : "+v"(a00), "+v"(a01), "+v"(a02), "+v"(a03));
    asm volatile("" : "+v"(a10), "+v"(a11), "+v"(a12), "+v"(a13));

    f32x4 esum0 = {0.f, 0.f, 0.f, 0.f};
    f32x4 esum1 = {0.f, 0.f, 0.f, 0.f};

    // Staging geometry: 1024 16B-chunks per tile, 4 per thread.
    // chunk d = j*256+tid -> col = j*16 + (tid>>4), seg = tid&15 (j-invariant).
    const int tcol = tid >> 4;        // 0..15
    const int tseg = tid & 15;
    const unsigned short* gsrc = Xc + (size_t)(cs * COLS_PER_CS + tcol) * DIM + tseg * 8;
    // LDS write chunk-slot for j=0 (j adds 256 chunks): swizzled seg ^ (col&7).
    const int lslot = (tcol << 4) | (tseg ^ (tcol & 7));

    // Prologue: issue loads for tile 0.
    bf16x8 st0, st1, st2, st3;
    st0 = *reinterpret_cast<const bf16x8*>(gsrc);
    st1 = *reinterpret_cast<const bf16x8*>(gsrc + 16 * DIM);
    st2 = *reinterpret_cast<const bf16x8*>(gsrc + 32 * DIM);
    st3 = *reinterpret_cast<const bf16x8*>(gsrc + 48 * DIM);

    for (int it = 0; it < NT; ++it) {
        if (it) __syncthreads();     // previous compute done reading LDS
        *reinterpret_cast<bf16x8*>(&Bt[(size_t)(lslot      ) * 8]) = st0;
        *reinterpret_cast<bf16x8*>(&Bt[(size_t)(lslot + 256) * 8]) = st1;
        *reinterpret_cast<bf16x8*>(&Bt[(size_t)(lslot + 512) * 8]) = st2;
        *reinterpret_cast<bf16x8*>(&Bt[(size_t)(lslot + 768) * 8]) = st3;
        __syncthreads();             // tile visible

        if (it + 1 < NT) {           // issue next tile's loads (no wait here)
            const unsigned short* nb = gsrc + (size_t)(it + 1) * CTILE * DIM;
            st0 = *reinterpret_cast<const bf16x8*>(nb);
            st1 = *reinterpret_cast<const bf16x8*>(nb + 16 * DIM);
            st2 = *reinterpret_cast<const bf16x8*>(nb + 32 * DIM);
            st3 = *reinterpret_cast<const bf16x8*>(nb + 48 * DIM);
        }

        const int x = l15 & 7;       // read-side swizzle (same involution)
#pragma unroll
        for (int ct = 0; ct < CTILE / 16; ++ct) {
            const unsigned short* lb = &Bt[(size_t)(ct * 16 + l15) * DIM];
            bf16x8 b0 = *reinterpret_cast<const bf16x8*>(lb + ((lhi      ^ x) * 8));
            bf16x8 b1 = *reinterpret_cast<const bf16x8*>(lb + (((lhi + 4 ) ^ x) * 8));
            bf16x8 b2 = *reinterpret_cast<const bf16x8*>(lb + (((lhi + 8 ) ^ x) * 8));
            bf16x8 b3 = *reinterpret_cast<const bf16x8*>(lb + (((lhi + 12) ^ x) * 8));

            f32x4 d0 = {0.f, 0.f, 0.f, 0.f};
            f32x4 d1 = {0.f, 0.f, 0.f, 0.f};
            d0 = __builtin_amdgcn_mfma_f32_16x16x32_bf16(a00, b0, d0, 0, 0, 0);
            d1 = __builtin_amdgcn_mfma_f32_16x16x32_bf16(a10, b0, d1, 0, 0, 0);
            d0 = __builtin_amdgcn_mfma_f32_16x16x32_bf16(a01, b1, d0, 0, 0, 0);
            d1 = __builtin_amdgcn_mfma_f32_16x16x32_bf16(a11, b1, d1, 0, 0, 0);
            d0 = __builtin_amdgcn_mfma_f32_16x16x32_bf16(a02, b2, d0, 0, 0, 0);
            d1 = __builtin_amdgcn_mfma_f32_16x16x32_bf16(a12, b2, d1, 0, 0, 0);
            d0 = __builtin_amdgcn_mfma_f32_16x16x32_bf16(a03, b3, d0, 0, 0, 0);
            d1 = __builtin_amdgcn_mfma_f32_16x16x32_bf16(a13, b3, d1, 0, 0, 0);

            esum0[0] += exp2_fast(d0[0]); esum0[1] += exp2_fast(d0[1]);
            esum0[2] += exp2_fast(d0[2]); esum0[3] += exp2_fast(d0[3]);
            esum1[0] += exp2_fast(d1[0]); esum1[1] += exp2_fast(d1[1]);
            esum1[2] += exp2_fast(d1[2]); esum1[3] += exp2_fast(d1[3]);
        }
    }

    // Reduce the 16 column-lanes (varying l15); one slot per row.
#pragma unroll
    for (int m = 0; m < MREP; ++m) {
#pragma unroll
        for (int j = 0; j < 4; ++j) {
            float v = (m == 0) ? esum0[j] : esum1[j];
            v += __shfl_xor(v, 1, 64);
            v += __shfl_xor(v, 2, 64);
            v += __shfl_xor(v, 4, 64);
            v += __shfl_xor(v, 8, 64);
            if (l15 == 0) {
                int row = rowbase + m * 16 + lhi * 4 + j;
                partial[(size_t)row * CSPLIT + cs] = v * E1_F;
            }
        }
    }
}

// Kernel 3: per-pair exact f32 2x2 block + D_pos + J^2, block-reduced.
__global__ __launch_bounds__(256) void k_loss1(const float* __restrict__ X,
                                               const float* __restrict__ partial,
                                               float* __restrict__ lpart) {
    int p = blockIdx.x * 256 + threadIdx.x;   // 0..4095
    const float4* a = reinterpret_cast<const float4*>(X + (size_t)(2 * p) * DIM);
    const float4* b = reinterpret_cast<const float4*>(X + (size_t)(2 * p + 1) * DIM);
    float d00 = 0.f, d01 = 0.f, d11 = 0.f;
#pragma unroll 8
    for (int i = 0; i < DIM / 4; ++i) {
        float4 av = a[i], bv = b[i];
        d00 += av.x * av.x + av.y * av.y + av.z * av.z + av.w * av.w;
        d01 += av.x * bv.x + av.y * bv.y + av.z * bv.z + av.w * bv.w;
        d11 += bv.x * bv.x + bv.y * bv.y + bv.z * bv.z + bv.w * bv.w;
    }
    float D01 = d01 * (1.0f / DIM);
    float blocksum = __expf(d00 * (1.0f / DIM) + 1.0f)
                   + 2.0f * __expf(D01 + 1.0f)
                   + __expf(d11 * (1.0f / DIM) + 1.0f);

    const float4* pp = reinterpret_cast<const float4*>(partial + (size_t)(2 * p) * CSPLIT);
    float S = 0.0f;
#pragma unroll
    for (int i = 0; i < 2 * CSPLIT / 4; ++i) {
        float4 v = pp[i];
        S += v.x + v.y + v.z + v.w;
    }
    S -= blocksum;
    float J = logf(1e-8f + S) - D01;
    float t = fmaxf(J, 0.0f);
    float acc = t * t;

    __shared__ float red[4];
    float v = acc;
#pragma unroll
    for (int off = 32; off >= 1; off >>= 1) v += __shfl_down(v, off, 64);
    if ((threadIdx.x & 63) == 0) red[threadIdx.x >> 6] = v;
    __syncthreads();
    if (threadIdx.x == 0)
        lpart[blockIdx.x] = red[0] + red[1] + red[2] + red[3];
}

// Kernel 4: final 16-element sum -> loss.
__global__ __launch_bounds__(64) void k_final(const float* __restrict__ lpart,
                                              float* __restrict__ out) {
    float v = (threadIdx.x < 16) ? lpart[threadIdx.x] : 0.0f;
#pragma unroll
    for (int off = 8; off >= 1; off >>= 1) v += __shfl_down(v, off, 64);
    if (threadIdx.x == 0) out[0] = v * (1.0f / (2.0f * NPAIR));
}

extern "C" void kernel_launch(void* const* d_in, const int* in_sizes, int n_in,
                              void* d_out, int out_size, void* d_ws, size_t ws_size,
                              hipStream_t stream) {
    const float* X = (const float*)d_in[0];
    float* out = (float*)d_out;

    unsigned short* Xa = (unsigned short*)d_ws;                        // 2 MB
    unsigned short* Xc = Xa + (size_t)NROWS * DIM;                     // 2 MB
    float* partial = (float*)(Xc + (size_t)NROWS * DIM);               // 512 KB
    float* lpart = partial + (size_t)NROWS * CSPLIT;                   // 64 B

    k_convert<<<dim3((NROWS * DIM / 4) / 256), dim3(256), 0, stream>>>(X, Xa, Xc);
    k_rowsum<<<dim3(NROWS / ROWS_PER_BLOCK, CSPLIT), dim3(256), 0, stream>>>(Xa, Xc, partial);
    k_loss1<<<dim3(NPAIR / 256), dim3(256), 0, stream>>>(X, partial, lpart);
    k_final<<<dim3(1), dim3(64), 0, stream>>>(lpart, out);
}